// Round 4
// baseline (113.193 us; speedup 1.0000x reference)
//
#include <hip/hip_runtime.h>
#include <math.h>

// Problem constants
#define H_   768
#define NH_  12
#define DH_  64
#define NL_  50
#define NCH_ 32      // number of 256-key subchunks
#define SC_  256     // keys per subchunk
#define NC_  16
#define S_   8192

typedef __attribute__((ext_vector_type(8))) short short8;
typedef __attribute__((ext_vector_type(4))) float f32x4;
typedef unsigned short u16;

#define AS1(p) ((const __attribute__((address_space(1))) void*)(p))
#define AS3(p) ((__attribute__((address_space(3))) void*)(p))

__device__ inline u16 f2b(float f) {
    union { float f; unsigned u; } x; x.f = f;
    return (u16)((x.u + 0x7FFFu + ((x.u >> 16) & 1u)) >> 16);
}

// ---------------------------------------------------------------------------
// prep_all: enc->bf16, ipw->bf16, lq->bf16(pad 128 rows), lw->bf16(pad),
// out_w -> bf16 transposed. Flat grid, ranges.
// ---------------------------------------------------------------------------
#define NB_ENC  6144
#define NB_IPW  1728
#define NB_LQ   96
#define NB_LW   96
#define NB_OWT  576

__global__ __launch_bounds__(256)
void prep_all(const float* __restrict__ enc, const float* __restrict__ ipw,
              const float* __restrict__ lq, const float* __restrict__ lwt,
              const float* __restrict__ ow,
              u16* __restrict__ encb, u16* __restrict__ ipwb,
              u16* __restrict__ lqb, u16* __restrict__ lwb, u16* __restrict__ owt)
{
    int b = blockIdx.x;
    const int t = threadIdx.x;
    if (b < NB_ENC) {
        const int i = b * 256 + t;
        const float4 v = reinterpret_cast<const float4*>(enc)[i];
        ushort4 o; o.x = f2b(v.x); o.y = f2b(v.y); o.z = f2b(v.z); o.w = f2b(v.w);
        reinterpret_cast<ushort4*>(encb)[i] = o;
        return;
    }
    b -= NB_ENC;
    if (b < NB_IPW) {
        const int i = b * 256 + t;
        const float4 v = reinterpret_cast<const float4*>(ipw)[i];
        ushort4 o; o.x = f2b(v.x); o.y = f2b(v.y); o.z = f2b(v.z); o.w = f2b(v.w);
        reinterpret_cast<ushort4*>(ipwb)[i] = o;
        return;
    }
    b -= NB_IPW;
    if (b < NB_LQ + NB_LW) {
        const bool isLw = (b >= NB_LQ);
        const int i = (isLw ? b - NB_LQ : b) * 256 + t;
        const int idx = i * 4, row = idx / H_, col = idx % H_;
        ushort4 o = make_ushort4(0, 0, 0, 0);
        if (row < NL_) {
            const float4 v = *reinterpret_cast<const float4*>(
                (isLw ? lwt : lq) + (long)row * H_ + col);
            o.x = f2b(v.x); o.y = f2b(v.y); o.z = f2b(v.z); o.w = f2b(v.w);
        }
        reinterpret_cast<ushort4*>(isLw ? lwb : lqb)[i] = o;
        return;
    }
    b -= NB_LQ + NB_LW;
    {
        const int i = b * 256 + t;
        const int idx = i * 4, h = idx / H_, j0 = idx % H_;
        ushort4 o;
        o.x = f2b(ow[(long)(j0 + 0) * H_ + h]);
        o.y = f2b(ow[(long)(j0 + 1) * H_ + h]);
        o.z = f2b(ow[(long)(j0 + 2) * H_ + h]);
        o.w = f2b(ow[(long)(j0 + 3) * H_ + h]);
        reinterpret_cast<ushort4*>(owt)[i] = o;
    }
}

// ---------------------------------------------------------------------------
// gemm_all: 128x128 tile, BK=32, double-buffered LDS with prefetch,
// XOR slot swizzle (conflict-free ds_read_b128), XCD-bijective tile remap.
//  by==0 : Q  (bx<6): lqb @ ipwb^T + ipb -> q_b bf16 *0.125
//  by==1 : M2 (bx<6): lwb @ owt^T -> M2f f32
//  by>=2 : KV : encb @ (ipwb+768*768)^T + ipb[768+] ->
//               n<768: k_b[row][n] ; n>=768: vt_b[n-768][row]
// ---------------------------------------------------------------------------
__global__ __launch_bounds__(256)
void gemm_all(const u16* __restrict__ encb, const u16* __restrict__ ipwb,
              const u16* __restrict__ lqb,  const u16* __restrict__ lwb,
              const u16* __restrict__ owt,  const float* __restrict__ ipb,
              u16* __restrict__ k_b, u16* __restrict__ vt_b,
              u16* __restrict__ q_b, float* __restrict__ M2f)
{
    int bx = blockIdx.x, by = blockIdx.y;
    const u16 *A, *B;
    const float* bias = nullptr;
    int mode;
    long m0 = 0;
    if (by == 0)      { if (bx >= 6) return; mode = 1; A = lqb; B = ipwb; bias = ipb; }
    else if (by == 1) { if (bx >= 6) return; mode = 2; A = lwb; B = owt; }
    else {
        mode = 0;
        const int flat = (by - 2) * 12 + bx;            // 0..767
        const int rem  = (flat & 7) * 96 + (flat >> 3); // XCD-bijective
        by = rem / 12; bx = rem % 12;
        A = encb; B = ipwb + (long)H_ * H_; bias = ipb + H_;
        m0 = (long)by * 128;
    }
    const long n0 = (long)bx * 128;

    __shared__ u16 As[2][4096];
    __shared__ u16 Bs[2][4096];

    const int tid  = threadIdx.x;
    const int lane = tid & 63;
    const int w    = tid >> 6;
    const int wr   = w >> 1, wc = w & 1;

    f32x4 acc[4][4];
    #pragma unroll
    for (int m = 0; m < 4; ++m)
        #pragma unroll
        for (int n = 0; n < 4; ++n)
            #pragma unroll
            for (int j = 0; j < 4; ++j) acc[m][n][j] = 0.f;

    const int sr0 = tid >> 2;     // staging row base (0..63)
    const int sp  = tid & 3;      // linear slot

    // prologue stage -> buf 0
    #pragma unroll
    for (int t = 0; t < 2; ++t) {
        const int row  = t * 64 + sr0;
        const int ss   = sp ^ ((row >> 1) & 3);
        const int ldso = (t * 256 + tid) * 8;
        __builtin_amdgcn_global_load_lds(AS1(A + (m0 + row) * H_ + ss * 8),
                                         AS3(As[0] + ldso), 16, 0, 0);
        __builtin_amdgcn_global_load_lds(AS1(B + (n0 + row) * H_ + ss * 8),
                                         AS3(Bs[0] + ldso), 16, 0, 0);
    }
    __syncthreads();

    const int rr = lane & 15, g = lane >> 4;
    const int ro = ((g ^ ((rr >> 1) & 3)) * 8);   // swizzled slot offset (elems)

    int cur = 0;
    for (int k0 = 32; k0 <= H_; k0 += 32) {
        if (k0 < H_) {
            #pragma unroll
            for (int t = 0; t < 2; ++t) {
                const int row  = t * 64 + sr0;
                const int ss   = sp ^ ((row >> 1) & 3);
                const int ldso = (t * 256 + tid) * 8;
                __builtin_amdgcn_global_load_lds(AS1(A + (m0 + row) * H_ + k0 + ss * 8),
                                                 AS3(As[cur ^ 1] + ldso), 16, 0, 0);
                __builtin_amdgcn_global_load_lds(AS1(B + (n0 + row) * H_ + k0 + ss * 8),
                                                 AS3(Bs[cur ^ 1] + ldso), 16, 0, 0);
            }
        }
        short8 a[4], bfr[4];
        #pragma unroll
        for (int m = 0; m < 4; ++m)
            a[m] = *reinterpret_cast<const short8*>(As[cur] + (wr * 64 + m * 16 + rr) * 32 + ro);
        #pragma unroll
        for (int n = 0; n < 4; ++n)
            bfr[n] = *reinterpret_cast<const short8*>(Bs[cur] + (wc * 64 + n * 16 + rr) * 32 + ro);
        #pragma unroll
        for (int m = 0; m < 4; ++m)
            #pragma unroll
            for (int n = 0; n < 4; ++n)
                acc[m][n] = __builtin_amdgcn_mfma_f32_16x16x32_bf16(a[m], bfr[n], acc[m][n], 0, 0, 0);
        __syncthreads();   // drains prefetch (vmcnt) + protects As[cur] reuse
        cur ^= 1;
    }

    // epilogue: C/D layout col=lane&15, row=(lane>>4)*4+j
    const int col16 = lane & 15, row4 = (lane >> 4) * 4;
    #pragma unroll
    for (int m = 0; m < 4; ++m) {
        #pragma unroll
        for (int n = 0; n < 4; ++n) {
            const long col = n0 + wc * 64 + n * 16 + col16;
            const float bv = bias ? bias[col] : 0.f;
            #pragma unroll
            for (int j = 0; j < 4; ++j) {
                const long row = m0 + wr * 64 + m * 16 + row4 + j;
                const float v = acc[m][n][j] + bv;
                if (mode == 0) {
                    if (col < H_) k_b[row * H_ + col] = f2b(v);
                    else          vt_b[(col - H_) * (long)S_ + row] = f2b(v);
                } else if (mode == 1) {
                    q_b[row * H_ + col] = f2b(v * 0.125f);
                } else {
                    M2f[row * H_ + col] = v;
                }
            }
        }
    }
}

// ---------------------------------------------------------------------------
// attn: block = (h, cc). 256 threads. 256-key subchunk partials, all 50 labels.
//  - K frags loaded DIRECTLY global->registers (zero reuse, skip LDS)
//  - V^T staged async via global_load_lds (swizzled source), consumed by PV
//  - P transposed through LDS (XOR slot swizzle)
//  - 3 barriers total
// ---------------------------------------------------------------------------
__global__ __launch_bounds__(256, 1)
void attn(const u16* __restrict__ q_b, const u16* __restrict__ k_b,
          const u16* __restrict__ vt_b,
          float* __restrict__ pm, float* __restrict__ pp, float* __restrict__ pctx)
{
    const int h  = blockIdx.x;   // 0..11
    const int cc = blockIdx.y;   // 0..31
    const int tid = threadIdx.x;
    const int lane = tid & 63;
    const int w    = tid >> 6;
    const int g    = lane >> 4;
    const int l15  = lane & 15;

    __shared__ u16 P[64 * 256];    // 32 KB
    __shared__ u16 Vb[64 * 256];   // 32 KB
    __shared__ float red[576];     // [0,256) wave max, [256,512) wave sum, [512,576) global max

    // --- issue V^T stage (64 d x 256 s), pre-swizzled source ---
    const long vbase = (long)h * DH_ * S_ + (long)cc * SC_;
    #pragma unroll
    for (int p = 0; p < 8; ++p) {
        const int d  = p * 8 + (tid >> 5);
        const int sc = (tid & 31) ^ (d & 15);
        __builtin_amdgcn_global_load_lds(AS1(vt_b + vbase + (long)d * S_ + sc * 8),
                                         AS3(Vb + p * 2048 + tid * 8), 16, 0, 0);
    }

    // --- Q fragments ---
    short8 aq[4][2];
    #pragma unroll
    for (int lt = 0; lt < 4; ++lt)
        #pragma unroll
        for (int ks = 0; ks < 2; ++ks)
            aq[lt][ks] = *reinterpret_cast<const short8*>(
                q_b + (long)(lt * 16 + l15) * H_ + h * DH_ + ks * 32 + g * 8);

    // --- K fragments direct from global (coalesced 16 rows x 64 B) ---
    const long kbase = (long)cc * SC_ * H_ + h * DH_;
    short8 bk[4][2];
    #pragma unroll
    for (int st = 0; st < 4; ++st)
        #pragma unroll
        for (int ks = 0; ks < 2; ++ks)
            bk[st][ks] = *reinterpret_cast<const short8*>(
                k_b + kbase + (long)(w * 64 + st * 16 + l15) * H_ + ks * 32 + g * 8);

    // --- QK^T: label l = lt*16+g*4+j, key s = w*64+st*16+l15 ---
    f32x4 acc[4][4];
    #pragma unroll
    for (int lt = 0; lt < 4; ++lt)
        #pragma unroll
        for (int st = 0; st < 4; ++st)
            #pragma unroll
            for (int j = 0; j < 4; ++j) acc[lt][st][j] = 0.f;
    #pragma unroll
    for (int ks = 0; ks < 2; ++ks)
        #pragma unroll
        for (int lt = 0; lt < 4; ++lt)
            #pragma unroll
            for (int st = 0; st < 4; ++st)
                acc[lt][st] = __builtin_amdgcn_mfma_f32_16x16x32_bf16(
                    aq[lt][ks], bk[st][ks], acc[lt][st], 0, 0, 0);

    // --- wave-local max (64 keys): in-lane 4 + shfl over 16 lanes ---
    #pragma unroll
    for (int lt = 0; lt < 4; ++lt)
        #pragma unroll
        for (int j = 0; j < 4; ++j) {
            float m = fmaxf(fmaxf(acc[lt][0][j], acc[lt][1][j]),
                            fmaxf(acc[lt][2][j], acc[lt][3][j]));
            #pragma unroll
            for (int o = 1; o < 16; o <<= 1) m = fmaxf(m, __shfl_xor(m, o));
            if (l15 == 0) red[w * 64 + lt * 16 + g * 4 + j] = m;
        }
    __syncthreads();   // [B1]
    if (tid < 64)
        red[512 + tid] = fmaxf(fmaxf(red[tid], red[64 + tid]),
                               fmaxf(red[128 + tid], red[192 + tid]));
    __syncthreads();   // [B2]

    // --- exp + P write (swizzled) + sum ---
    float mg[4][4];
    #pragma unroll
    for (int lt = 0; lt < 4; ++lt)
        #pragma unroll
        for (int j = 0; j < 4; ++j) mg[lt][j] = red[512 + lt * 16 + g * 4 + j];
    #pragma unroll
    for (int lt = 0; lt < 4; ++lt)
        #pragma unroll
        for (int st = 0; st < 4; ++st)
            #pragma unroll
            for (int j = 0; j < 4; ++j)
                acc[lt][st][j] = __expf(acc[lt][st][j] - mg[lt][j]);
    #pragma unroll
    for (int lt = 0; lt < 4; ++lt)
        #pragma unroll
        for (int st = 0; st < 4; ++st)
            #pragma unroll
            for (int j = 0; j < 4; ++j) {
                const int l  = lt * 16 + g * 4 + j;
                const int sl = w * 64 + st * 16 + l15;
                const int byte = l * 512 + ((sl * 2) ^ ((l & 15) << 4));
                *(u16*)((char*)P + byte) = f2b(acc[lt][st][j]);
            }
    #pragma unroll
    for (int lt = 0; lt < 4; ++lt)
        #pragma unroll
        for (int j = 0; j < 4; ++j) {
            float s = acc[lt][0][j] + acc[lt][1][j] + acc[lt][2][j] + acc[lt][3][j];
            #pragma unroll
            for (int o = 1; o < 16; o <<= 1) s += __shfl_xor(s, o);
            if (l15 == 0) red[256 + w * 64 + lt * 16 + g * 4 + j] = s;
        }
    __syncthreads();   // [B3] P visible, sums ready, V stage drained (vmcnt 0)

    if (tid < NL_) {
        const long idx = ((long)cc * NH_ + h) * NL_ + tid;
        pm[idx] = red[512 + tid];
        pp[idx] = red[256 + tid] + red[320 + tid] + red[384 + tid] + red[448 + tid];
    }

    // --- PV: wave w owns labels [w*16, w*16+16) ---
    f32x4 acc2[4];
    #pragma unroll
    for (int dt = 0; dt < 4; ++dt)
        #pragma unroll
        for (int j = 0; j < 4; ++j) acc2[dt][j] = 0.f;

    const int lrow = w * 16 + l15;
    const int lx   = l15 << 4;
    #pragma unroll
    for (int ks = 0; ks < 8; ++ks) {
        const int ch = ks * 4 + g;
        const short8 pa = *reinterpret_cast<const short8*>(
            (const char*)P + lrow * 512 + ((ch << 4) ^ lx));
        #pragma unroll
        for (int dt = 0; dt < 4; ++dt) {
            const int dl = dt * 16 + l15;
            const short8 vb = *reinterpret_cast<const short8*>(
                (const char*)Vb + dl * 512 + ((ch ^ l15) << 4));
            acc2[dt] = __builtin_amdgcn_mfma_f32_16x16x32_bf16(pa, vb, acc2[dt], 0, 0, 0);
        }
    }

    #pragma unroll
    for (int dt = 0; dt < 4; ++dt)
        #pragma unroll
        for (int j = 0; j < 4; ++j) {
            const int l = w * 16 + g * 4 + j;
            if (l < NL_) {
                const long idx = ((long)cc * NH_ + h) * NL_ + l;
                pctx[idx * DH_ + dt * 16 + l15] = acc2[dt][j];
            }
        }
}

// ---------------------------------------------------------------------------
// combine_score: block = label l. Prefix-combine 32 subchunk partials; emit
// score at every 2nd subchunk (chunk boundary).
// ---------------------------------------------------------------------------
__global__ __launch_bounds__(256)
void combine_score(const float* __restrict__ pm, const float* __restrict__ pp,
                   const float* __restrict__ pctx, const float* __restrict__ M2f,
                   const float* __restrict__ lw, const float* __restrict__ ob,
                   float* __restrict__ out)
{
    const int l = blockIdx.x;
    const int tid = threadIdx.x;
    const int w = tid >> 6, lane = tid & 63;
    __shared__ float wred[4], bred[4];

    float bp = 0.f;
    #pragma unroll
    for (int r = 0; r < 3; ++r) {
        const int i = tid + 256 * r;
        bp += lw[(long)l * H_ + i] * ob[i];
    }
    #pragma unroll
    for (int o = 1; o < 64; o <<= 1) bp += __shfl_xor(bp, o);
    if (lane == 0) bred[w] = bp;

    float M[3], Ssum[3], A[3];
    #pragma unroll
    for (int r = 0; r < 3; ++r) { M[r] = -INFINITY; Ssum[r] = 0.f; A[r] = 0.f; }

    for (int cc = 0; cc < NCH_; ++cc) {
        #pragma unroll
        for (int r = 0; r < 3; ++r) {
            const int i = tid + 256 * r;
            const int hh = i >> 6, d = i & 63;
            const long idx = ((long)cc * NH_ + hh) * NL_ + l;
            const float mc = pm[idx], pc = pp[idx];
            const float Mn = fmaxf(M[r], mc);
            const float ea = __expf(M[r] - Mn), eb = __expf(mc - Mn);
            Ssum[r] = Ssum[r] * ea + pc * eb;
            A[r]    = A[r] * ea + pctx[idx * DH_ + d] * eb;
            M[r] = Mn;
        }
        if (cc & 1) {
            float t = 0.f;
            #pragma unroll
            for (int r = 0; r < 3; ++r) {
                const int i = tid + 256 * r;
                t += (A[r] / Ssum[r]) * M2f[(long)l * H_ + i];
            }
            #pragma unroll
            for (int o = 1; o < 64; o <<= 1) t += __shfl_xor(t, o);
            if (lane == 0) wred[w] = t;
            __syncthreads();
            if (tid == 0)
                out[(long)(cc >> 1) * NL_ + l] = wred[0] + wred[1] + wred[2] + wred[3]
                                               + bred[0] + bred[1] + bred[2] + bred[3];
            __syncthreads();
        }
    }
}

// ---------------------------------------------------------------------------
extern "C" void kernel_launch(void* const* d_in, const int* in_sizes, int n_in,
                              void* d_out, int out_size, void* d_ws, size_t ws_size,
                              hipStream_t stream) {
    const float* enc = (const float*)d_in[0];
    const float* lq  = (const float*)d_in[1];
    const float* lwt = (const float*)d_in[2];
    const float* ipw = (const float*)d_in[3];
    const float* ipb = (const float*)d_in[4];
    const float* ow  = (const float*)d_in[5];
    const float* ob  = (const float*)d_in[6];
    float* out = (float*)d_out;

    // workspace: f32 region then bf16 region (16B aligned throughout)
    float* wsf  = (float*)d_ws;
    float* pctx = wsf;                                    // 32*12*50*64 = 1228800
    float* M2f  = pctx + (long)NCH_ * NH_ * NL_ * DH_;    // 128*768
    float* pm   = M2f + (long)128 * H_;                   // 19200
    float* pp   = pm + (long)NCH_ * NH_ * NL_;            // 19200
    u16* encb = (u16*)(pp + (long)NCH_ * NH_ * NL_);      // 8192*768
    u16* ipwb = encb + (long)S_ * H_;                     // 2304*768
    u16* lqb  = ipwb + (long)3 * H_ * H_;                 // 128*768
    u16* lwb  = lqb + (long)128 * H_;                     // 128*768
    u16* owt  = lwb + (long)128 * H_;                     // 768*768
    u16* q_b  = owt + (long)H_ * H_;                      // 128*768
    u16* k_b  = q_b + (long)128 * H_;                     // 8192*768
    u16* vt_b = k_b + (long)S_ * H_;                      // 768*8192

    prep_all<<<dim3(NB_ENC + NB_IPW + NB_LQ + NB_LW + NB_OWT), 256, 0, stream>>>(
        enc, ipw, lq, lwt, ow, encb, ipwb, lqb, lwb, owt);

    gemm_all<<<dim3(12, 66), 256, 0, stream>>>(
        encb, ipwb, lqb, lwb, owt, ipb, k_b, vt_b, q_b, M2f);

    attn<<<dim3(NH_, NCH_), 256, 0, stream>>>(q_b, k_b, vt_b, pm, pp, pctx);

    combine_score<<<dim3(NL_), 256, 0, stream>>>(pm, pp, pctx, M2f, lwt, ob, out);
}

// Round 5
// 107.768 us; speedup vs baseline: 1.0503x; 1.0503x over previous
//
#include <hip/hip_runtime.h>
#include <math.h>

// Problem constants
#define H_   768
#define NH_  12
#define DH_  64
#define NL_  50
#define NCH_ 32      // number of 256-key subchunks
#define SC_  256     // keys per subchunk
#define NC_  16
#define S_   8192

typedef __attribute__((ext_vector_type(8))) short short8;
typedef __attribute__((ext_vector_type(4))) float f32x4;
typedef unsigned short u16;

#define AS1(p) ((const __attribute__((address_space(1))) void*)(p))
#define AS3(p) ((__attribute__((address_space(3))) void*)(p))

__device__ inline u16 f2b(float f) {
    union { float f; unsigned u; } x; x.f = f;
    return (u16)((x.u + 0x7FFFu + ((x.u >> 16) & 1u)) >> 16);
}

// ---------------------------------------------------------------------------
// prep_all: enc->bf16, ipw->bf16, lq->bf16(pad 128 rows), lw->bf16(pad),
// out_w -> bf16 transposed. Flat grid, ranges.
// ---------------------------------------------------------------------------
#define NB_ENC  6144
#define NB_IPW  1728
#define NB_LQ   96
#define NB_LW   96
#define NB_OWT  576

__global__ __launch_bounds__(256)
void prep_all(const float* __restrict__ enc, const float* __restrict__ ipw,
              const float* __restrict__ lq, const float* __restrict__ lwt,
              const float* __restrict__ ow,
              u16* __restrict__ encb, u16* __restrict__ ipwb,
              u16* __restrict__ lqb, u16* __restrict__ lwb, u16* __restrict__ owt)
{
    int b = blockIdx.x;
    const int t = threadIdx.x;
    if (b < NB_ENC) {
        const int i = b * 256 + t;
        const float4 v = reinterpret_cast<const float4*>(enc)[i];
        ushort4 o; o.x = f2b(v.x); o.y = f2b(v.y); o.z = f2b(v.z); o.w = f2b(v.w);
        reinterpret_cast<ushort4*>(encb)[i] = o;
        return;
    }
    b -= NB_ENC;
    if (b < NB_IPW) {
        const int i = b * 256 + t;
        const float4 v = reinterpret_cast<const float4*>(ipw)[i];
        ushort4 o; o.x = f2b(v.x); o.y = f2b(v.y); o.z = f2b(v.z); o.w = f2b(v.w);
        reinterpret_cast<ushort4*>(ipwb)[i] = o;
        return;
    }
    b -= NB_IPW;
    if (b < NB_LQ + NB_LW) {
        const bool isLw = (b >= NB_LQ);
        const int i = (isLw ? b - NB_LQ : b) * 256 + t;
        const int idx = i * 4, row = idx / H_, col = idx % H_;
        ushort4 o = make_ushort4(0, 0, 0, 0);
        if (row < NL_) {
            const float4 v = *reinterpret_cast<const float4*>(
                (isLw ? lwt : lq) + (long)row * H_ + col);
            o.x = f2b(v.x); o.y = f2b(v.y); o.z = f2b(v.z); o.w = f2b(v.w);
        }
        reinterpret_cast<ushort4*>(isLw ? lwb : lqb)[i] = o;
        return;
    }
    b -= NB_LQ + NB_LW;
    {
        const int i = b * 256 + t;
        const int idx = i * 4, h = idx / H_, j0 = idx % H_;
        ushort4 o;
        o.x = f2b(ow[(long)(j0 + 0) * H_ + h]);
        o.y = f2b(ow[(long)(j0 + 1) * H_ + h]);
        o.z = f2b(ow[(long)(j0 + 2) * H_ + h]);
        o.w = f2b(ow[(long)(j0 + 3) * H_ + h]);
        reinterpret_cast<ushort4*>(owt)[i] = o;
    }
}

// ---------------------------------------------------------------------------
// gemm_all: 128x128 tile, BK=32. 3-buffer rotation + COUNTED vmcnt(4) +
// raw s_barrier: loads span 2 full K-steps (true pipeline depth 2), no
// vmcnt(0) drain in the main loop. XOR slot swizzle (0 bank conflicts),
// XCD-bijective tile remap (L2-local A/B panels).
//  by==0 : Q  (bx<6): lqb @ ipwb^T + ipb -> q_b bf16 *0.125
//  by==1 : M2 (bx<6): lwb @ owt^T -> M2f f32
//  by>=2 : KV : encb @ (ipwb+768*768)^T + ipb[768+] ->
//               n<768: k_b[row][n] ; n>=768: vt_b[n-768][row]
// ---------------------------------------------------------------------------
#define NT_ 24   // K-steps (768/32)

__global__ __launch_bounds__(256)
void gemm_all(const u16* __restrict__ encb, const u16* __restrict__ ipwb,
              const u16* __restrict__ lqb,  const u16* __restrict__ lwb,
              const u16* __restrict__ owt,  const float* __restrict__ ipb,
              u16* __restrict__ k_b, u16* __restrict__ vt_b,
              u16* __restrict__ q_b, float* __restrict__ M2f)
{
    int bx = blockIdx.x, by = blockIdx.y;
    const u16 *A, *B;
    const float* bias = nullptr;
    int mode;
    long m0 = 0;
    if (by == 0)      { if (bx >= 6) return; mode = 1; A = lqb; B = ipwb; bias = ipb; }
    else if (by == 1) { if (bx >= 6) return; mode = 2; A = lwb; B = owt; }
    else {
        mode = 0;
        const int flat = (by - 2) * 12 + bx;            // 0..767
        const int rem  = (flat & 7) * 96 + (flat >> 3); // XCD-bijective
        by = rem / 12; bx = rem % 12;
        A = encb; B = ipwb + (long)H_ * H_; bias = ipb + H_;
        m0 = (long)by * 128;
    }
    const long n0 = (long)bx * 128;

    __shared__ u16 As[3][4096];   // 24 KB
    __shared__ u16 Bs[3][4096];   // 24 KB

    const int tid  = threadIdx.x;
    const int lane = tid & 63;
    const int w    = tid >> 6;
    const int wr   = w >> 1, wc = w & 1;

    f32x4 acc[4][4];
    #pragma unroll
    for (int m = 0; m < 4; ++m)
        #pragma unroll
        for (int n = 0; n < 4; ++n)
            #pragma unroll
            for (int j = 0; j < 4; ++j) acc[m][n][j] = 0.f;

    const int sr0 = tid >> 2;     // staging row base (0..63)
    const int sp  = tid & 3;      // linear slot

    auto stage = [&](int t, int buf) {
        const int k0 = t * 32;
        #pragma unroll
        for (int tt = 0; tt < 2; ++tt) {
            const int row  = tt * 64 + sr0;
            const int ss   = sp ^ ((row >> 1) & 3);
            const int ldso = (tt * 256 + tid) * 8;
            __builtin_amdgcn_global_load_lds(AS1(A + (m0 + row) * H_ + k0 + ss * 8),
                                             AS3(As[buf] + ldso), 16, 0, 0);
            __builtin_amdgcn_global_load_lds(AS1(B + (n0 + row) * H_ + k0 + ss * 8),
                                             AS3(Bs[buf] + ldso), 16, 0, 0);
        }
    };

    // prologue: tiles 0 and 1 in flight
    stage(0, 0);
    stage(1, 1);

    const int rr = lane & 15, g = lane >> 4;
    const int ro = ((g ^ ((rr >> 1) & 3)) * 8);   // swizzled slot offset (elems)

    for (int t = 0; t < NT_; ++t) {
        // wait: tile t landed (tiles t+1, t+2 may stay in flight), then publish
        if (t < NT_ - 1) asm volatile("s_waitcnt vmcnt(4)" ::: "memory");
        else             asm volatile("s_waitcnt vmcnt(0)" ::: "memory");
        __builtin_amdgcn_s_barrier();
        __builtin_amdgcn_sched_barrier(0);   // nothing moves above the barrier

        const int cb = t % 3;
        short8 a[4], bfr[4];
        #pragma unroll
        for (int m = 0; m < 4; ++m)
            a[m] = *reinterpret_cast<const short8*>(As[cb] + (wr * 64 + m * 16 + rr) * 32 + ro);
        #pragma unroll
        for (int n = 0; n < 4; ++n)
            bfr[n] = *reinterpret_cast<const short8*>(Bs[cb] + (wc * 64 + n * 16 + rr) * 32 + ro);
        #pragma unroll
        for (int m = 0; m < 4; ++m)
            #pragma unroll
            for (int n = 0; n < 4; ++n)
                acc[m][n] = __builtin_amdgcn_mfma_f32_16x16x32_bf16(a[m], bfr[n], acc[m][n], 0, 0, 0);

        // prefetch tile t+2 into the buffer freed at iter t-1
        if (t + 2 < NT_) stage(t + 2, (t + 2) % 3);
    }

    // epilogue: C/D layout col=lane&15, row=(lane>>4)*4+j
    const int col16 = lane & 15, row4 = (lane >> 4) * 4;
    #pragma unroll
    for (int m = 0; m < 4; ++m) {
        #pragma unroll
        for (int n = 0; n < 4; ++n) {
            const long col = n0 + wc * 64 + n * 16 + col16;
            const float bv = bias ? bias[col] : 0.f;
            #pragma unroll
            for (int j = 0; j < 4; ++j) {
                const long row = m0 + wr * 64 + m * 16 + row4 + j;
                const float v = acc[m][n][j] + bv;
                if (mode == 0) {
                    if (col < H_) k_b[row * H_ + col] = f2b(v);
                    else          vt_b[(col - H_) * (long)S_ + row] = f2b(v);
                } else if (mode == 1) {
                    q_b[row * H_ + col] = f2b(v * 0.125f);
                } else {
                    M2f[row * H_ + col] = v;
                }
            }
        }
    }
}

// ---------------------------------------------------------------------------
// attn: block = (h, cc). 256 threads. 256-key subchunk partials, all 50 labels.
//  - K frags loaded DIRECTLY global->registers (zero reuse, skip LDS)
//  - V^T staged async via global_load_lds (swizzled source), consumed by PV
//  - P transposed through LDS (XOR slot swizzle)
// ---------------------------------------------------------------------------
__global__ __launch_bounds__(256, 1)
void attn(const u16* __restrict__ q_b, const u16* __restrict__ k_b,
          const u16* __restrict__ vt_b,
          float* __restrict__ pm, float* __restrict__ pp, float* __restrict__ pctx)
{
    const int h  = blockIdx.x;   // 0..11
    const int cc = blockIdx.y;   // 0..31
    const int tid = threadIdx.x;
    const int lane = tid & 63;
    const int w    = tid >> 6;
    const int g    = lane >> 4;
    const int l15  = lane & 15;

    __shared__ u16 P[64 * 256];    // 32 KB
    __shared__ u16 Vb[64 * 256];   // 32 KB
    __shared__ float red[576];     // [0,256) wave max, [256,512) wave sum, [512,576) global max

    // --- issue V^T stage (64 d x 256 s), pre-swizzled source ---
    const long vbase = (long)h * DH_ * S_ + (long)cc * SC_;
    #pragma unroll
    for (int p = 0; p < 8; ++p) {
        const int d  = p * 8 + (tid >> 5);
        const int sc = (tid & 31) ^ (d & 15);
        __builtin_amdgcn_global_load_lds(AS1(vt_b + vbase + (long)d * S_ + sc * 8),
                                         AS3(Vb + p * 2048 + tid * 8), 16, 0, 0);
    }

    // --- Q fragments ---
    short8 aq[4][2];
    #pragma unroll
    for (int lt = 0; lt < 4; ++lt)
        #pragma unroll
        for (int ks = 0; ks < 2; ++ks)
            aq[lt][ks] = *reinterpret_cast<const short8*>(
                q_b + (long)(lt * 16 + l15) * H_ + h * DH_ + ks * 32 + g * 8);

    // --- K fragments direct from global (coalesced 16 rows x 64 B) ---
    const long kbase = (long)cc * SC_ * H_ + h * DH_;
    short8 bk[4][2];
    #pragma unroll
    for (int st = 0; st < 4; ++st)
        #pragma unroll
        for (int ks = 0; ks < 2; ++ks)
            bk[st][ks] = *reinterpret_cast<const short8*>(
                k_b + kbase + (long)(w * 64 + st * 16 + l15) * H_ + ks * 32 + g * 8);

    // --- QK^T: label l = lt*16+g*4+j, key s = w*64+st*16+l15 ---
    f32x4 acc[4][4];
    #pragma unroll
    for (int lt = 0; lt < 4; ++lt)
        #pragma unroll
        for (int st = 0; st < 4; ++st)
            #pragma unroll
            for (int j = 0; j < 4; ++j) acc[lt][st][j] = 0.f;
    #pragma unroll
    for (int ks = 0; ks < 2; ++ks)
        #pragma unroll
        for (int lt = 0; lt < 4; ++lt)
            #pragma unroll
            for (int st = 0; st < 4; ++st)
                acc[lt][st] = __builtin_amdgcn_mfma_f32_16x16x32_bf16(
                    aq[lt][ks], bk[st][ks], acc[lt][st], 0, 0, 0);

    // --- wave-local max (64 keys): in-lane 4 + shfl over 16 lanes ---
    #pragma unroll
    for (int lt = 0; lt < 4; ++lt)
        #pragma unroll
        for (int j = 0; j < 4; ++j) {
            float m = fmaxf(fmaxf(acc[lt][0][j], acc[lt][1][j]),
                            fmaxf(acc[lt][2][j], acc[lt][3][j]));
            #pragma unroll
            for (int o = 1; o < 16; o <<= 1) m = fmaxf(m, __shfl_xor(m, o));
            if (l15 == 0) red[w * 64 + lt * 16 + g * 4 + j] = m;
        }
    __syncthreads();   // [B1]
    if (tid < 64)
        red[512 + tid] = fmaxf(fmaxf(red[tid], red[64 + tid]),
                               fmaxf(red[128 + tid], red[192 + tid]));
    __syncthreads();   // [B2]

    // --- exp + P write (swizzled) + sum ---
    float mg[4][4];
    #pragma unroll
    for (int lt = 0; lt < 4; ++lt)
        #pragma unroll
        for (int j = 0; j < 4; ++j) mg[lt][j] = red[512 + lt * 16 + g * 4 + j];
    #pragma unroll
    for (int lt = 0; lt < 4; ++lt)
        #pragma unroll
        for (int st = 0; st < 4; ++st)
            #pragma unroll
            for (int j = 0; j < 4; ++j)
                acc[lt][st][j] = __expf(acc[lt][st][j] - mg[lt][j]);
    #pragma unroll
    for (int lt = 0; lt < 4; ++lt)
        #pragma unroll
        for (int st = 0; st < 4; ++st)
            #pragma unroll
            for (int j = 0; j < 4; ++j) {
                const int l  = lt * 16 + g * 4 + j;
                const int sl = w * 64 + st * 16 + l15;
                const int byte = l * 512 + ((sl * 2) ^ ((l & 15) << 4));
                *(u16*)((char*)P + byte) = f2b(acc[lt][st][j]);
            }
    #pragma unroll
    for (int lt = 0; lt < 4; ++lt)
        #pragma unroll
        for (int j = 0; j < 4; ++j) {
            float s = acc[lt][0][j] + acc[lt][1][j] + acc[lt][2][j] + acc[lt][3][j];
            #pragma unroll
            for (int o = 1; o < 16; o <<= 1) s += __shfl_xor(s, o);
            if (l15 == 0) red[256 + w * 64 + lt * 16 + g * 4 + j] = s;
        }
    __syncthreads();   // [B3] P visible, sums ready, V stage drained (vmcnt 0)

    if (tid < NL_) {
        const long idx = ((long)cc * NH_ + h) * NL_ + tid;
        pm[idx] = red[512 + tid];
        pp[idx] = red[256 + tid] + red[320 + tid] + red[384 + tid] + red[448 + tid];
    }

    // --- PV: wave w owns labels [w*16, w*16+16) ---
    f32x4 acc2[4];
    #pragma unroll
    for (int dt = 0; dt < 4; ++dt)
        #pragma unroll
        for (int j = 0; j < 4; ++j) acc2[dt][j] = 0.f;

    const int lrow = w * 16 + l15;
    const int lx   = l15 << 4;
    #pragma unroll
    for (int ks = 0; ks < 8; ++ks) {
        const int ch = ks * 4 + g;
        const short8 pa = *reinterpret_cast<const short8*>(
            (const char*)P + lrow * 512 + ((ch << 4) ^ lx));
        #pragma unroll
        for (int dt = 0; dt < 4; ++dt) {
            const int dl = dt * 16 + l15;
            const short8 vb = *reinterpret_cast<const short8*>(
                (const char*)Vb + dl * 512 + ((ch ^ l15) << 4));
            acc2[dt] = __builtin_amdgcn_mfma_f32_16x16x32_bf16(pa, vb, acc2[dt], 0, 0, 0);
        }
    }

    #pragma unroll
    for (int dt = 0; dt < 4; ++dt)
        #pragma unroll
        for (int j = 0; j < 4; ++j) {
            const int l = w * 16 + g * 4 + j;
            if (l < NL_) {
                const long idx = ((long)cc * NH_ + h) * NL_ + l;
                pctx[idx * DH_ + dt * 16 + l15] = acc2[dt][j];
            }
        }
}

// ---------------------------------------------------------------------------
// combine_score: block = label l. Prefix-combine 32 subchunk partials; emit
// score at every 2nd subchunk (chunk boundary).
// ---------------------------------------------------------------------------
__global__ __launch_bounds__(256)
void combine_score(const float* __restrict__ pm, const float* __restrict__ pp,
                   const float* __restrict__ pctx, const float* __restrict__ M2f,
                   const float* __restrict__ lw, const float* __restrict__ ob,
                   float* __restrict__ out)
{
    const int l = blockIdx.x;
    const int tid = threadIdx.x;
    const int w = tid >> 6, lane = tid & 63;
    __shared__ float wred[4], bred[4];

    float bp = 0.f;
    #pragma unroll
    for (int r = 0; r < 3; ++r) {
        const int i = tid + 256 * r;
        bp += lw[(long)l * H_ + i] * ob[i];
    }
    #pragma unroll
    for (int o = 1; o < 64; o <<= 1) bp += __shfl_xor(bp, o);
    if (lane == 0) bred[w] = bp;

    float M[3], Ssum[3], A[3];
    #pragma unroll
    for (int r = 0; r < 3; ++r) { M[r] = -INFINITY; Ssum[r] = 0.f; A[r] = 0.f; }

    for (int cc = 0; cc < NCH_; ++cc) {
        #pragma unroll
        for (int r = 0; r < 3; ++r) {
            const int i = tid + 256 * r;
            const int hh = i >> 6, d = i & 63;
            const long idx = ((long)cc * NH_ + hh) * NL_ + l;
            const float mc = pm[idx], pc = pp[idx];
            const float Mn = fmaxf(M[r], mc);
            const float ea = __expf(M[r] - Mn), eb = __expf(mc - Mn);
            Ssum[r] = Ssum[r] * ea + pc * eb;
            A[r]    = A[r] * ea + pctx[idx * DH_ + d] * eb;
            M[r] = Mn;
        }
        if (cc & 1) {
            float t = 0.f;
            #pragma unroll
            for (int r = 0; r < 3; ++r) {
                const int i = tid + 256 * r;
                t += (A[r] / Ssum[r]) * M2f[(long)l * H_ + i];
            }
            #pragma unroll
            for (int o = 1; o < 64; o <<= 1) t += __shfl_xor(t, o);
            if (lane == 0) wred[w] = t;
            __syncthreads();
            if (tid == 0)
                out[(long)(cc >> 1) * NL_ + l] = wred[0] + wred[1] + wred[2] + wred[3]
                                               + bred[0] + bred[1] + bred[2] + bred[3];
            __syncthreads();
        }
    }
}

// ---------------------------------------------------------------------------
extern "C" void kernel_launch(void* const* d_in, const int* in_sizes, int n_in,
                              void* d_out, int out_size, void* d_ws, size_t ws_size,
                              hipStream_t stream) {
    const float* enc = (const float*)d_in[0];
    const float* lq  = (const float*)d_in[1];
    const float* lwt = (const float*)d_in[2];
    const float* ipw = (const float*)d_in[3];
    const float* ipb = (const float*)d_in[4];
    const float* ow  = (const float*)d_in[5];
    const float* ob  = (const float*)d_in[6];
    float* out = (float*)d_out;

    // workspace: f32 region then bf16 region (16B aligned throughout)
    float* wsf  = (float*)d_ws;
    float* pctx = wsf;                                    // 32*12*50*64 = 1228800
    float* M2f  = pctx + (long)NCH_ * NH_ * NL_ * DH_;    // 128*768
    float* pm   = M2f + (long)128 * H_;                   // 19200
    float* pp   = pm + (long)NCH_ * NH_ * NL_;            // 19200
    u16* encb = (u16*)(pp + (long)NCH_ * NH_ * NL_);      // 8192*768
    u16* ipwb = encb + (long)S_ * H_;                     // 2304*768
    u16* lqb  = ipwb + (long)3 * H_ * H_;                 // 128*768
    u16* lwb  = lqb + (long)128 * H_;                     // 128*768
    u16* owt  = lwb + (long)128 * H_;                     // 768*768
    u16* q_b  = owt + (long)H_ * H_;                      // 128*768
    u16* k_b  = q_b + (long)128 * H_;                     // 8192*768
    u16* vt_b = k_b + (long)S_ * H_;                      // 768*8192

    prep_all<<<dim3(NB_ENC + NB_IPW + NB_LQ + NB_LW + NB_OWT), 256, 0, stream>>>(
        enc, ipw, lq, lwt, ow, encb, ipwb, lqb, lwb, owt);

    gemm_all<<<dim3(12, 66), 256, 0, stream>>>(
        encb, ipwb, lqb, lwb, owt, ipb, k_b, vt_b, q_b, M2f);

    attn<<<dim3(NH_, NCH_), 256, 0, stream>>>(q_b, k_b, vt_b, pm, pp, pctx);

    combine_score<<<dim3(NL_), 256, 0, stream>>>(pm, pp, pctx, M2f, lwt, ob, out);
}